// Round 2
// baseline (20329.700 us; speedup 1.0000x reference)
//
#include <hip/hip_runtime.h>
#include <cmath>

#define BATCH 256
#define TSEQ  256
#define ISZ   32
#define HSZ   512
#define OSZ   32
#define FUT   128

// Persistent-kernel decomposition:
//   grid = 256 WGs = bg(4 batch groups x 64 rows) x ng(64 hidden groups x 8 hidden)
//   block = 512 threads = 8 waves (2 waves/SIMD)
//   wave wv owns batch octet bg*64 + wv*8; lane: r = lane&31 (gate-row),
//   bhalf = lane>>5 (which 4-batch quad of the octet).
//   WG's 32 gate-rows: global row = (r>>3)*512 + ng*8 + (r&7)   [i,f,g,o layout]
//   W_hh slice (64 KB) lives in LDS for the whole 384-step sequence.
//   h is double-buffered in ws, stored TRANSPOSED [hidden][batch] for coalescing.
//   c never leaves registers. Sync = per-bg-group barrier (64 WGs, agent scope).

__device__ __forceinline__ float sigm(float x) { return 1.0f / (1.0f + expf(-x)); }

struct WsLayout {
    unsigned* cnt;      // [4]
    unsigned* flag;     // [4]
    float* hA;          // [512][256]
    float* hB;          // [512][256]
    float* pred;        // [256][32]
};

__device__ __forceinline__ void bg_barrier(unsigned* cnt, unsigned* flag, int bg,
                                           unsigned token)
{
    __syncthreads();
    if (threadIdx.x == 0) {
        __threadfence();  // agent-scope: push h/pred stores past XCD L2
        unsigned prev = __hip_atomic_fetch_add(&cnt[bg], 1u, __ATOMIC_ACQ_REL,
                                               __HIP_MEMORY_SCOPE_AGENT);
        if (prev + 1u == token * 64u) {
            __hip_atomic_store(&flag[bg], token, __ATOMIC_RELEASE,
                               __HIP_MEMORY_SCOPE_AGENT);
        } else {
            while (__hip_atomic_load(&flag[bg], __ATOMIC_ACQUIRE,
                                     __HIP_MEMORY_SCOPE_AGENT) < token) { }
        }
    }
    __syncthreads();
}

__global__ __launch_bounds__(512, 2) void lstm_persistent(
    const float* __restrict__ x,
    const float* __restrict__ W_ih, const float* __restrict__ W_hh,
    const float* __restrict__ b_ih, const float* __restrict__ b_hh,
    const float* __restrict__ W_fc, const float* __restrict__ b_fc,
    float* __restrict__ out,
    unsigned* cnt, unsigned* flag,
    float* hA, float* hB, float* predbuf)
{
    __shared__ float w_lds[32][512];   // swizzled: col = k ^ ((r&15)<<2)
    __shared__ float wih_t[32][32];    // [kk][r]
    __shared__ float wfc_lds[512];
    __shared__ float bias_lds[32];
    __shared__ float redbuf[8][64];

    const int tid  = (int)threadIdx.x;
    const int bg   = (int)blockIdx.x & 3;
    const int ng   = (int)blockIdx.x >> 2;
    const int wv   = tid >> 6;
    const int lane = tid & 63;
    const int r    = lane & 31;        // local gate-row
    const int bhalf= lane >> 5;
    const int bbase= bg * 64 + wv * 8 + bhalf * 4;  // first of this lane's 4 batches
    const int o    = ng & 31;          // FC output column this WG (redundantly) computes

    // ---- one-time init: stage weights into LDS ----
    for (int i = tid; i < 32 * 512; i += 512) {
        int rr = i >> 9, k = i & 511;
        int grow = (rr >> 3) * HSZ + ng * 8 + (rr & 7);
        w_lds[rr][k ^ ((rr & 15) << 2)] = W_hh[grow * HSZ + k];
    }
    for (int i = tid; i < 32 * 32; i += 512) {
        int rr = i >> 5, kk = i & 31;
        int grow = (rr >> 3) * HSZ + ng * 8 + (rr & 7);
        wih_t[kk][rr] = W_ih[grow * ISZ + kk];
    }
    if (tid < 32) {
        int grow = (tid >> 3) * HSZ + ng * 8 + (tid & 7);
        bias_lds[tid] = b_ih[grow] + b_hh[grow];
    }
    if (tid < 512) {
        // guard always true; single pass
        wfc_lds[tid] = W_fc[o * HSZ + tid];
    }
    const float bfc = b_fc[o];
    __syncthreads();

    float c0 = 0.f, c1 = 0.f, c2 = 0.f, c3 = 0.f;   // cell state, persists in VGPRs
    unsigned token = 0;
    float* ha = hA;   // read buffer
    float* hb = hB;   // write buffer

    const int swz = (r & 15) << 2;
    const float* wrow = &w_lds[r][0];

    for (int t = 0; t < TSEQ + FUT - 1; ++t) {
        const bool enc = (t < TSEQ);
        const float* xsrc = enc ? (x + (size_t)t * ISZ) : predbuf;
        const int xstride = enc ? (TSEQ * ISZ) : OSZ;

        // ---- gates = bias + x@W_ih^T + h@W_hh^T for this lane's (4b x row r) ----
        float acc0 = bias_lds[r];
        float acc1 = acc0, acc2 = acc0, acc3 = acc0;

        // x part (K = 32)
        #pragma unroll
        for (int kk = 0; kk < ISZ; kk += 4) {
            float4 x0 = *(const float4*)(xsrc + (size_t)(bbase + 0) * xstride + kk);
            float4 x1 = *(const float4*)(xsrc + (size_t)(bbase + 1) * xstride + kk);
            float4 x2 = *(const float4*)(xsrc + (size_t)(bbase + 2) * xstride + kk);
            float4 x3 = *(const float4*)(xsrc + (size_t)(bbase + 3) * xstride + kk);
            float w0 = wih_t[kk + 0][r], w1 = wih_t[kk + 1][r];
            float w2 = wih_t[kk + 2][r], w3 = wih_t[kk + 3][r];
            acc0 += x0.x * w0 + x0.y * w1 + x0.z * w2 + x0.w * w3;
            acc1 += x1.x * w0 + x1.y * w1 + x1.z * w2 + x1.w * w3;
            acc2 += x2.x * w0 + x2.y * w1 + x2.z * w2 + x2.w * w3;
            acc3 += x3.x * w0 + x3.y * w1 + x3.z * w2 + x3.w * w3;
        }

        // h part (K = 512): h transposed [k][256b]; W row from swizzled LDS
        #pragma unroll 2
        for (int k = 0; k < HSZ; k += 8) {
            float4 wa = *(const float4*)(wrow + ((k + 0) ^ swz));
            float4 wb4 = *(const float4*)(wrow + ((k + 4) ^ swz));
            float4 h0 = *(const float4*)(ha + (size_t)(k + 0) * BATCH + bbase);
            float4 h1 = *(const float4*)(ha + (size_t)(k + 1) * BATCH + bbase);
            float4 h2 = *(const float4*)(ha + (size_t)(k + 2) * BATCH + bbase);
            float4 h3 = *(const float4*)(ha + (size_t)(k + 3) * BATCH + bbase);
            float4 h4 = *(const float4*)(ha + (size_t)(k + 4) * BATCH + bbase);
            float4 h5 = *(const float4*)(ha + (size_t)(k + 5) * BATCH + bbase);
            float4 h6 = *(const float4*)(ha + (size_t)(k + 6) * BATCH + bbase);
            float4 h7 = *(const float4*)(ha + (size_t)(k + 7) * BATCH + bbase);
            acc0 += h0.x * wa.x + h1.x * wa.y + h2.x * wa.z + h3.x * wa.w
                  + h4.x * wb4.x + h5.x * wb4.y + h6.x * wb4.z + h7.x * wb4.w;
            acc1 += h0.y * wa.x + h1.y * wa.y + h2.y * wa.z + h3.y * wa.w
                  + h4.y * wb4.x + h5.y * wb4.y + h6.y * wb4.z + h7.y * wb4.w;
            acc2 += h0.z * wa.x + h1.z * wa.y + h2.z * wa.z + h3.z * wa.w
                  + h4.z * wb4.x + h5.z * wb4.y + h6.z * wb4.z + h7.z * wb4.w;
            acc3 += h0.w * wa.x + h1.w * wa.y + h2.w * wa.z + h3.w * wa.w
                  + h4.w * wb4.x + h5.w * wb4.y + h6.w * wb4.z + h7.w * wb4.w;
        }

        // ---- gather gate quad: xor 8 flips gate bit0, 16 bit1, 24 both ----
        float f0 = __shfl_xor(acc0, 8),  f1 = __shfl_xor(acc1, 8);
        float f2 = __shfl_xor(acc2, 8),  f3 = __shfl_xor(acc3, 8);
        float g0 = __shfl_xor(acc0, 16), g1 = __shfl_xor(acc1, 16);
        float g2 = __shfl_xor(acc2, 16), g3 = __shfl_xor(acc3, 16);
        float q0 = __shfl_xor(acc0, 24), q1 = __shfl_xor(acc1, 24);
        float q2 = __shfl_xor(acc2, 24), q3 = __shfl_xor(acc3, 24);

        if (r < 8) {  // these lanes hold gate i; partners supplied f,g,o
            float i0 = sigm(acc0), i1 = sigm(acc1), i2 = sigm(acc2), i3 = sigm(acc3);
            float F0 = sigm(f0),   F1 = sigm(f1),   F2 = sigm(f2),   F3 = sigm(f3);
            float G0 = tanhf(g0),  G1 = tanhf(g1),  G2 = tanhf(g2),  G3 = tanhf(g3);
            float O0 = sigm(q0),   O1 = sigm(q1),   O2 = sigm(q2),   O3 = sigm(q3);
            c0 = F0 * c0 + i0 * G0;  c1 = F1 * c1 + i1 * G1;
            c2 = F2 * c2 + i2 * G2;  c3 = F3 * c3 + i3 * G3;
            float4 hv = make_float4(O0 * tanhf(c0), O1 * tanhf(c1),
                                    O2 * tanhf(c2), O3 * tanhf(c3));
            *(float4*)(hb + (size_t)(ng * 8 + r) * BATCH + bbase) = hv;
        }

        ++token;
        bg_barrier(cnt, flag, bg, token);
        { float* tmp = ha; ha = hb; hb = tmp; }   // ha now holds the new h

        // ---- decoder: compute pred = h @ W_fc^T + b_fc after each step that
        //      needs it (last encoder step and every decoder step) ----
        if (t >= TSEQ - 1) {
            const int step = t - (TSEQ - 1);   // output index 0..127
            const int b = tid & 63, ks = tid >> 6;
            float a = 0.f;
            const float* hp = ha + (size_t)(ks * 64) * BATCH + bg * 64 + b;
            #pragma unroll 8
            for (int j = 0; j < 64; ++j) a += hp[(size_t)j * BATCH] * wfc_lds[ks * 64 + j];
            redbuf[ks][b] = a;
            __syncthreads();
            if (tid < 64) {
                float s = bfc;
                #pragma unroll
                for (int q = 0; q < 8; ++q) s += redbuf[q][tid];
                if (ng < 32) {
                    predbuf[(size_t)(bg * 64 + tid) * OSZ + o] = s;
                    out[(size_t)(bg * 64 + tid) * (FUT * OSZ) + (size_t)step * OSZ + o] = s;
                }
            }
            ++token;
            bg_barrier(cnt, flag, bg, token);
        }
    }
}

extern "C" void kernel_launch(void* const* d_in, const int* in_sizes, int n_in,
                              void* d_out, int out_size, void* d_ws, size_t ws_size,
                              hipStream_t stream)
{
    (void)in_sizes; (void)n_in; (void)out_size; (void)ws_size;
    const float* x    = (const float*)d_in[0];
    const float* W_ih = (const float*)d_in[1];
    const float* W_hh = (const float*)d_in[2];
    const float* b_ih = (const float*)d_in[3];
    const float* b_hh = (const float*)d_in[4];
    const float* W_fc = (const float*)d_in[5];
    const float* b_fc = (const float*)d_in[6];
    float* out = (float*)d_out;

    char* ws = (char*)d_ws;
    unsigned* cnt  = (unsigned*)ws;                       // [4]
    unsigned* flag = (unsigned*)(ws + 128);               // [4]
    float* hA      = (float*)(ws + 256);                  // 512 KB
    float* hB      = (float*)(ws + 256 + (512u << 10));   // 512 KB
    float* predbuf = (float*)(ws + 256 + (1024u << 10));  // 32 KB

    // zero barrier state + hA (initial hidden state); c is zeroed in-kernel
    hipMemsetAsync(ws, 0, 256 + (512u << 10), stream);

    lstm_persistent<<<256, 512, 0, stream>>>(
        x, W_ih, W_hh, b_ih, b_hh, W_fc, b_fc, out,
        cnt, flag, hA, hB, predbuf);
}

// Round 3
// 9945.052 us; speedup vs baseline: 2.0442x; 2.0442x over previous
//
#include <hip/hip_runtime.h>
#include <cmath>

#define BATCH 256
#define TSEQ  256
#define ISZ   32
#define HSZ   512
#define OSZ   32
#define FUT   128

typedef float  f32x4 __attribute__((ext_vector_type(4)));
typedef short  s16x8 __attribute__((ext_vector_type(8)));
typedef unsigned int       uint32;
typedef unsigned long long u64;
typedef unsigned short     u16;

#define MFMA_BF16 __builtin_amdgcn_mfma_f32_16x16x32_bf16

__device__ __forceinline__ float sigm(float v) { return 1.0f / (1.0f + __expf(-v)); }

// ---------------- weight pre-split: fp32 -> (bf16 hi, bf16 lo) planes ----------------
__global__ __launch_bounds__(256) void split_weights(
    const float* __restrict__ Whh, const float* __restrict__ Wih,
    const float* __restrict__ Wfc, const float* __restrict__ bih,
    const float* __restrict__ bhh,
    u16* WhhH, u16* WhhL, u16* WihH, u16* WihL, u16* WfcH, u16* WfcL,
    float* bsum)
{
    const int i = blockIdx.x * 256 + (int)threadIdx.x;
    // segments: Whh 1048576 | Wih 65536 | Wfc 16384 | bias 2048
    if (i < 1048576) {
        float v = Whh[i];
        uint32 u = __float_as_uint(v), hu = u & 0xFFFF0000u;
        float rs = v - __uint_as_float(hu);
        WhhH[i] = (u16)(u >> 16); WhhL[i] = (u16)(__float_as_uint(rs) >> 16);
    } else if (i < 1114112) {
        int j = i - 1048576;
        float v = Wih[j];
        uint32 u = __float_as_uint(v), hu = u & 0xFFFF0000u;
        float rs = v - __uint_as_float(hu);
        WihH[j] = (u16)(u >> 16); WihL[j] = (u16)(__float_as_uint(rs) >> 16);
    } else if (i < 1130496) {
        int j = i - 1114112;
        float v = Wfc[j];
        uint32 u = __float_as_uint(v), hu = u & 0xFFFF0000u;
        float rs = v - __uint_as_float(hu);
        WfcH[j] = (u16)(u >> 16); WfcL[j] = (u16)(__float_as_uint(rs) >> 16);
    } else if (i < 1132544) {
        int j = i - 1130496;
        bsum[j] = bih[j] + bhh[j];
    }
}

// ---------------- persistent MFMA LSTM ----------------
// grid 256 = bg(4 batch groups x 64) x ng(64 hidden groups x 8)
// block 512 = 8 waves: wave w -> (m = w>>2, n = w&3) 16x16 C tile of
// gates[32 rows][64 batches]; rows r: grow = (r>>3)*512 + ng*8 + (r&7)  [i,f,g,o]
// h exchanged as packed u32 (bf16hi<<16 | bf16lo), layout hT[b][512k], double-buffered.
// All cross-WG data via relaxed AGENT atomics (IF$ coherence point, no cache fences).
__global__ __launch_bounds__(512, 2) void lstm_mfma(
    const float* __restrict__ x, const float* __restrict__ b_fc,
    float* __restrict__ out,
    const u16* __restrict__ WhhH, const u16* __restrict__ WhhL,
    const u16* __restrict__ WihH, const u16* __restrict__ WihL,
    const u16* __restrict__ WfcH, const u16* __restrict__ WfcL,
    const float* __restrict__ bsum,
    uint32* hT0, uint32* hT1,
    uint32* arrive, uint32* bcast)
{
    __shared__ float gatebuf[32][68];
    __shared__ u16 predH[64][40];
    __shared__ u16 predL[64][40];

    const int tid = (int)threadIdx.x;
    const int bg = (int)blockIdx.x & 3, ng = (int)blockIdx.x >> 2;
    const int w = tid >> 6, l = tid & 63;
    const int m = w >> 2, n = w & 3;
    const int ks = l >> 4, lcol = l & 15;

    // A (weights) addressing: lane row = m*16+lcol, k = ks*8 + j
    const int r = m * 16 + lcol;
    const int grow = (r >> 3) * 512 + ng * 8 + (r & 7);
    const u16* whhH_p = WhhH + grow * 512 + ks * 8;
    const u16* whhL_p = WhhL + grow * 512 + ks * 8;
    const u16* wihH_p = WihH + grow * 32 + ks * 8;
    const u16* wihL_p = WihL + grow * 32 + ks * 8;
    const u16* wfcH_p = WfcH + r * 512 + ks * 8;   // pred A rows = o = r (0..31)
    const u16* wfcL_p = WfcL + r * 512 + ks * 8;

    // B (h) addressing: lane col = batch bcol, elements packed u32 along k
    const int bcol = bg * 64 + n * 16 + lcol;
    const int bofs_u64 = bcol * 256 + ks * 4;      // u64 index: (bcol*512 + ks*8)/2

    // epilogue state mapping: 1 (hidden,batch) cell per thread
    const int h8 = tid & 7, be = tid >> 3;
    const int hidx = (bg * 64 + be) * 512 + ng * 8 + h8;
    const float bi  = bsum[       ng * 8 + h8];
    const float bf  = bsum[ 512 + ng * 8 + h8];
    const float bgg = bsum[1024 + ng * 8 + h8];
    const float bo  = bsum[1536 + ng * 8 + h8];
    float pb[4];
    #pragma unroll
    for (int q = 0; q < 4; ++q) pb[q] = b_fc[m * 16 + ks * 4 + q];

    float cst = 0.f;

    for (int tt = 0; tt < TSEQ + FUT; ++tt) {
        const uint32* hre = (tt & 1) ? hT0 : hT1;
        uint32*       hwr = (tt & 1) ? hT1 : hT0;
        const u64* bp = (const u64*)hre + bofs_u64;

        f32x4 gA = {0,0,0,0}, gB = {0,0,0,0}, gC = {0,0,0,0};
        f32x4 pA = {0,0,0,0}, pB = {0,0,0,0}, pC = {0,0,0,0};
        const bool hash = (tt > 0);
        const bool dec  = (tt >= TSEQ);

        u64 tA[16], tB[16];
        if (hash) {   // issue first 8 k-tiles of B (deep vmcnt pipelining, no waits)
            #pragma unroll
            for (int j = 0; j < 16; ++j)
                tA[j] = __hip_atomic_load((u64*)(bp + (0 + (j >> 2)) * 16 + (j & 3)),
                                          __ATOMIC_RELAXED, __HIP_MEMORY_SCOPE_AGENT);
            #pragma unroll
            for (int j = 0; j < 16; ++j)
                tB[j] = __hip_atomic_load((u64*)(bp + (4 + (j >> 2)) * 16 + (j & 3)),
                                          __ATOMIC_RELAXED, __HIP_MEMORY_SCOPE_AGENT);
        }

        // ---- k-tile0 (x input) for encoder ----
        if (!dec) {
            const float* xp = x + (size_t)bcol * (TSEQ * ISZ) + (size_t)tt * ISZ + ks * 8;
            float xv[8];
            *(float4*)&xv[0] = *(const float4*)xp;
            *(float4*)&xv[4] = *(const float4*)(xp + 4);
            s16x8 xh, xl;
            uint32* ph = (uint32*)&xh; uint32* pl = (uint32*)&xl;
            #pragma unroll
            for (int q = 0; q < 4; ++q) {
                uint32 u0 = __float_as_uint(xv[2*q]),   h0 = u0 & 0xFFFF0000u;
                uint32 u1 = __float_as_uint(xv[2*q+1]), h1 = u1 & 0xFFFF0000u;
                float r0 = xv[2*q]   - __uint_as_float(h0);
                float r1 = xv[2*q+1] - __uint_as_float(h1);
                ph[q] = (h0 >> 16) | h1;
                pl[q] = (__float_as_uint(r0) >> 16) | (__float_as_uint(r1) & 0xFFFF0000u);
            }
            s16x8 ih = *(const s16x8*)wihH_p;
            s16x8 il = *(const s16x8*)wihL_p;
            gA = MFMA_BF16(ih, xh, gA, 0, 0, 0);
            gB = MFMA_BF16(ih, xl, gB, 0, 0, 0);
            gC = MFMA_BF16(il, xh, gC, 0, 0, 0);
        }

        // ---- main h k-tiles: unpack + 3 gate MFMAs (+3 pred MFMAs in decoder) ----
#define CONSUME4(ARR, KTBASE)                                                   \
        {                                                                       \
            _Pragma("unroll")                                                   \
            for (int j2 = 0; j2 < 4; ++j2) {                                    \
                const int kt = (KTBASE) + j2;                                   \
                s16x8 bhi, blo;                                                 \
                uint32* bh = (uint32*)&bhi; uint32* bl = (uint32*)&blo;         \
                _Pragma("unroll")                                               \
                for (int q = 0; q < 4; ++q) {                                   \
                    uint32 a0 = (uint32)ARR[j2*4+q];                            \
                    uint32 a1 = (uint32)(ARR[j2*4+q] >> 32);                    \
                    bh[q] = (a0 >> 16) | (a1 & 0xFFFF0000u);                    \
                    bl[q] = (a0 & 0xFFFFu) | (a1 << 16);                        \
                }                                                               \
                s16x8 ah = *(const s16x8*)(whhH_p + kt * 32);                   \
                s16x8 al = *(const s16x8*)(whhL_p + kt * 32);                   \
                gA = MFMA_BF16(ah, bhi, gA, 0, 0, 0);                           \
                gB = MFMA_BF16(ah, blo, gB, 0, 0, 0);                           \
                gC = MFMA_BF16(al, bhi, gC, 0, 0, 0);                           \
                if (dec) {                                                      \
                    s16x8 fh = *(const s16x8*)(wfcH_p + kt * 32);               \
                    s16x8 fl = *(const s16x8*)(wfcL_p + kt * 32);               \
                    pA = MFMA_BF16(fh, bhi, pA, 0, 0, 0);                       \
                    pB = MFMA_BF16(fh, blo, pB, 0, 0, 0);                       \
                    pC = MFMA_BF16(fl, bhi, pC, 0, 0, 0);                       \
                }                                                               \
            }                                                                   \
        }
#define LOADG(ARR, KTBASE)                                                      \
        {                                                                       \
            _Pragma("unroll")                                                   \
            for (int j = 0; j < 16; ++j)                                        \
                ARR[j] = __hip_atomic_load(                                     \
                    (u64*)(bp + ((KTBASE) + (j >> 2)) * 16 + (j & 3)),          \
                    __ATOMIC_RELAXED, __HIP_MEMORY_SCOPE_AGENT);                \
        }
        if (hash) {
            CONSUME4(tA, 0);  LOADG(tA, 8);
            CONSUME4(tB, 4);  LOADG(tB, 12);
            CONSUME4(tA, 8);
            CONSUME4(tB, 12);
        }
#undef CONSUME4
#undef LOADG

        // ---- decoder: pred epilogue, then k-tile0 from predbuf ----
        if (dec) {
            f32x4 pr = pA + pB + pC;
            const int step = tt - TSEQ;
            #pragma unroll
            for (int q = 0; q < 4; ++q) {
                float pv = pr[q] + pb[q];
                int oc = m * 16 + ks * 4 + q;
                uint32 u = __float_as_uint(pv), hu = u & 0xFFFF0000u;
                float rs = pv - __uint_as_float(hu);
                predH[n * 16 + lcol][oc] = (u16)(u >> 16);
                predL[n * 16 + lcol][oc] = (u16)(__float_as_uint(rs) >> 16);
                out[(size_t)bcol * (FUT * OSZ) + (size_t)step * OSZ + oc] = pv;
            }
            __syncthreads();
            s16x8 bh = *(const s16x8*)&predH[n * 16 + lcol][ks * 8];
            s16x8 bl = *(const s16x8*)&predL[n * 16 + lcol][ks * 8];
            s16x8 ih = *(const s16x8*)wihH_p;
            s16x8 il = *(const s16x8*)wihL_p;
            gA = MFMA_BF16(ih, bh, gA, 0, 0, 0);
            gB = MFMA_BF16(ih, bl, gB, 0, 0, 0);
            gC = MFMA_BF16(il, bh, gC, 0, 0, 0);
        }

        // ---- gate combine -> LDS bounce -> cell update -> publish h ----
        f32x4 gt = gA + gB + gC;
        #pragma unroll
        for (int q = 0; q < 4; ++q)
            gatebuf[m * 16 + ks * 4 + q][n * 16 + lcol] = gt[q];
        __syncthreads();

        {
            float gi = gatebuf[h8][be] + bi;
            float gf = gatebuf[h8 + 8][be] + bf;
            float gg = gatebuf[h8 + 16][be] + bgg;
            float go = gatebuf[h8 + 24][be] + bo;
            cst = sigm(gf) * cst + sigm(gi) * tanhf(gg);
            float hv = sigm(go) * tanhf(cst);
            uint32 u = __float_as_uint(hv), hu = u & 0xFFFF0000u;
            float rs = hv - __uint_as_float(hu);
            uint32 pk = hu | (__float_as_uint(rs) >> 16);
            __hip_atomic_store(hwr + hidx, pk, __ATOMIC_RELAXED, __HIP_MEMORY_SCOPE_AGENT);
        }

        // ---- barrier: vmcnt drain -> 4-domain arrive/broadcast, relaxed + sleep ----
        asm volatile("s_waitcnt vmcnt(0)" ::: "memory");
        __syncthreads();
        const uint32 token = (uint32)(tt + 1);
        if (ng == 0) {
            if (tid < 64) {
                if (tid > 0) {
                    int guard = 0;
                    while (__hip_atomic_load(arrive + (bg * 64 + tid) * 16,
                                             __ATOMIC_RELAXED, __HIP_MEMORY_SCOPE_AGENT) < token
                           && guard < (1 << 18)) { __builtin_amdgcn_s_sleep(1); ++guard; }
                }
                if (tid == 0)
                    __hip_atomic_store(bcast + bg * 16, token,
                                       __ATOMIC_RELAXED, __HIP_MEMORY_SCOPE_AGENT);
            }
        } else {
            if (tid == 0) {
                __hip_atomic_store(arrive + (bg * 64 + ng) * 16, token,
                                   __ATOMIC_RELAXED, __HIP_MEMORY_SCOPE_AGENT);
                int guard = 0;
                while (__hip_atomic_load(bcast + bg * 16,
                                         __ATOMIC_RELAXED, __HIP_MEMORY_SCOPE_AGENT) < token
                       && guard < (1 << 18)) { __builtin_amdgcn_s_sleep(1); ++guard; }
            }
        }
        __syncthreads();
    }
}

extern "C" void kernel_launch(void* const* d_in, const int* in_sizes, int n_in,
                              void* d_out, int out_size, void* d_ws, size_t ws_size,
                              hipStream_t stream)
{
    (void)in_sizes; (void)n_in; (void)out_size; (void)ws_size;
    const float* x    = (const float*)d_in[0];
    const float* W_ih = (const float*)d_in[1];
    const float* W_hh = (const float*)d_in[2];
    const float* b_ih = (const float*)d_in[3];
    const float* b_hh = (const float*)d_in[4];
    const float* W_fc = (const float*)d_in[5];
    const float* b_fc = (const float*)d_in[6];
    float* out = (float*)d_out;

    char* ws = (char*)d_ws;
    uint32* arrive = (uint32*)(ws + 0);            // 16 KB (padded slots)
    uint32* bcast  = (uint32*)(ws + 16384);        // 256 B
    uint32* hT0    = (uint32*)(ws + 65536);        // 512 KB packed h
    uint32* hT1    = (uint32*)(ws + 589824);       // 512 KB
    u16* WhhH = (u16*)(ws + 1114112);              // 2 MB
    u16* WhhL = (u16*)(ws + 3211264);              // 2 MB
    u16* WihH = (u16*)(ws + 5308416);              // 128 KB
    u16* WihL = (u16*)(ws + 5439488);              // 128 KB
    u16* WfcH = (u16*)(ws + 5570560);              // 32 KB
    u16* WfcL = (u16*)(ws + 5603328);              // 32 KB
    float* bsum = (float*)(ws + 5636096);          // 8 KB

    hipMemsetAsync(ws, 0, 16640, stream);          // arrive + bcast only

    split_weights<<<4424, 256, 0, stream>>>(W_hh, W_ih, W_fc, b_ih, b_hh,
                                            WhhH, WhhL, WihH, WihL, WfcH, WfcL, bsum);

    lstm_mfma<<<256, 512, 0, stream>>>(x, b_fc, out,
                                       WhhH, WhhL, WihH, WihL, WfcH, WfcL, bsum,
                                       hT0, hT1, arrive, bcast);
}

// Round 4
// 3794.539 us; speedup vs baseline: 5.3576x; 2.6209x over previous
//
#include <hip/hip_runtime.h>
#include <cmath>

#define BATCH 256
#define TSEQ  256
#define ISZ   32
#define HSZ   512
#define OSZ   32
#define FUT   128

typedef float  f32x4 __attribute__((ext_vector_type(4)));
typedef short  s16x8 __attribute__((ext_vector_type(8)));
typedef unsigned int   uint32;
typedef unsigned short u16;

#define MFMA_BF16 __builtin_amdgcn_mfma_f32_16x16x32_bf16

__device__ __forceinline__ float sigm(float v) { return 1.0f / (1.0f + __expf(-v)); }

// ---- MALL-coherent (cross-XCD) access helpers: sc0 sc1 bypass L1+L2 ----
template<int OFF>
__device__ __forceinline__ s16x8 ldB_cc(const u16* p) {
    s16x8 d;
    asm volatile("global_load_dwordx4 %0, %1, off offset:%2 sc0 sc1"
                 : "=v"(d) : "v"(p), "n"(OFF) : "memory");
    return d;
}
template<int OFF>
__device__ __forceinline__ f32x4 ldx16(const float* p) {   // normal cached
    f32x4 d;
    asm volatile("global_load_dwordx4 %0, %1, off offset:%2"
                 : "=v"(d) : "v"(p), "n"(OFF) : "memory");
    return d;
}
__device__ __forceinline__ void st16_cc(u16* p, uint32 v) {
    asm volatile("global_store_short %0, %1, off sc0 sc1" :: "v"(p), "v"(v) : "memory");
}
__device__ __forceinline__ void st32_cc(uint32* p, uint32 v) {
    asm volatile("global_store_dword %0, %1, off sc0 sc1" :: "v"(p), "v"(v) : "memory");
}
__device__ __forceinline__ uint32 ld32_cc(const uint32* p) {
    uint32 d;
    asm volatile("global_load_dword %0, %1, off sc0 sc1" : "=v"(d) : "v"(p) : "memory");
    return d;
}
#define WAITV(N) do { asm volatile("s_waitcnt vmcnt(" #N ")" ::: "memory"); \
                      __builtin_amdgcn_sched_barrier(0); } while (0)

// ---------------- weight pre-split: fp32 -> (bf16 hi, bf16 lo) planes ----------------
__global__ __launch_bounds__(256) void split_weights(
    const float* __restrict__ Whh, const float* __restrict__ Wih,
    const float* __restrict__ Wfc, const float* __restrict__ bih,
    const float* __restrict__ bhh,
    u16* WhhH, u16* WhhL, u16* WihH, u16* WihL, u16* WfcH, u16* WfcL,
    float* bsum)
{
    const int i = blockIdx.x * 256 + (int)threadIdx.x;
    if (i < 1048576) {
        float v = Whh[i];
        uint32 u = __float_as_uint(v), hu = u & 0xFFFF0000u;
        float rs = v - __uint_as_float(hu);
        WhhH[i] = (u16)(u >> 16); WhhL[i] = (u16)(__float_as_uint(rs) >> 16);
    } else if (i < 1114112) {
        int j = i - 1048576;
        float v = Wih[j];
        uint32 u = __float_as_uint(v), hu = u & 0xFFFF0000u;
        float rs = v - __uint_as_float(hu);
        WihH[j] = (u16)(u >> 16); WihL[j] = (u16)(__float_as_uint(rs) >> 16);
    } else if (i < 1130496) {
        int j = i - 1114112;
        float v = Wfc[j];
        uint32 u = __float_as_uint(v), hu = u & 0xFFFF0000u;
        float rs = v - __uint_as_float(hu);
        WfcH[j] = (u16)(u >> 16); WfcL[j] = (u16)(__float_as_uint(rs) >> 16);
    } else if (i < 1132544) {
        int j = i - 1130496;
        bsum[j] = bih[j] + bhh[j];
    }
}

// ---------------- persistent MFMA LSTM ----------------
// grid 256 = bg(4 batch groups x 64) x ng(64 hidden groups x 8); block 512 = 8 waves.
// wave w: (m = w>>2, n = w&3) 16x16 C tile of gates[32 rows][64 batches].
// All weights LDS-resident (swizzled). h exchanged as TWO bf16 planes [b][k]
// via sc0/sc1 (MALL-coherent) asm loads/stores, double-buffered.
// Barrier: all-poll on 64 padded slots per batch-domain.
__global__ __launch_bounds__(512, 1) void lstm_mfma(
    const float* __restrict__ x, const float* __restrict__ b_fc,
    float* __restrict__ out,
    const u16* __restrict__ WhhHg, const u16* __restrict__ WhhLg,
    const u16* __restrict__ WihHg, const u16* __restrict__ WihLg,
    const u16* __restrict__ WfcHg, const u16* __restrict__ WfcLg,
    const float* __restrict__ bsum,
    u16* hHi0, u16* hLo0, u16* hHi1, u16* hLo1,
    uint32* arrive)
{
    __shared__ __align__(16) u16 whhHi[32 * 512];
    __shared__ __align__(16) u16 whhLo[32 * 512];
    __shared__ __align__(16) u16 wfcHi[32 * 512];
    __shared__ __align__(16) u16 wfcLo[32 * 512];
    __shared__ float gatebuf[32][68];
    __shared__ __align__(16) u16 predH[64][40];
    __shared__ __align__(16) u16 predL[64][40];

    const int tid = (int)threadIdx.x;
    const int bg = (int)blockIdx.x & 3, ng = (int)blockIdx.x >> 2;
    const int w = tid >> 6, l = tid & 63;
    const int m = w >> 2, n = w & 3;
    const int ks = l >> 4, lcol = l & 15;

    // ---- stage all weights into LDS (swizzled: granule g -> g ^ (row&7)) ----
    for (int i = tid; i < 32 * 512; i += 512) {
        int rr = i >> 9, k = i & 511;
        int dst = (rr << 9) + ((((k >> 3) ^ (rr & 7)) << 3) | (k & 7));
        int gr = (rr >> 3) * HSZ + ng * 8 + (rr & 7);
        whhHi[dst] = WhhHg[gr * HSZ + k];
        whhLo[dst] = WhhLg[gr * HSZ + k];
        wfcHi[dst] = WfcHg[(rr << 9) + k];
        wfcLo[dst] = WfcLg[(rr << 9) + k];
    }

    // A addressing: lane row r = m*16+lcol, k = ks*8 + j
    const int r = m * 16 + lcol;
    const int rswz = r & 7;
    const int awB = r << 9;                 // row base (u16 index)
    const int grow = (r >> 3) * HSZ + ng * 8 + (r & 7);

    // Wih fragments live in registers for the whole kernel
    const s16x8 ihH = *(const s16x8*)(WihHg + (size_t)grow * ISZ + ks * 8);
    const s16x8 ihL = *(const s16x8*)(WihLg + (size_t)grow * ISZ + ks * 8);

    // B addressing
    const int bcol = (bg << 6) + (n << 4) + lcol;
    const size_t boff = (size_t)bcol * HSZ + ks * 8;
    const u16* hiP0 = hHi0 + boff; const u16* loP0 = hLo0 + boff;
    const u16* hiP1 = hHi1 + boff; const u16* loP1 = hLo1 + boff;
    const float* xbase = x + (size_t)bcol * (TSEQ * ISZ) + ks * 8;
    float* outp = out + (size_t)bcol * (FUT * OSZ);

    // epilogue mapping: one (hidden,batch) cell per thread
    const int h8 = tid & 7, be = tid >> 3;
    const size_t hoff = (size_t)((bg << 6) + be) * HSZ + ng * 8 + h8;
    const float bi  = bsum[       ng * 8 + h8];
    const float bf  = bsum[ 512 + ng * 8 + h8];
    const float bgg = bsum[1024 + ng * 8 + h8];
    const float bo  = bsum[1536 + ng * 8 + h8];
    float pb[4];
    #pragma unroll
    for (int q = 0; q < 4; ++q) pb[q] = b_fc[m * 16 + ks * 4 + q];

    uint32* myslot = arrive + (((bg << 6) + ng) << 4);
    const uint32* pollbase = arrive + ((bg << 6) << 4);

    float cst = 0.f;
    __syncthreads();

#define ISSUE_KT(KT) do { bh[KT] = ldB_cc<(KT)*64>(hiP); bl[KT] = ldB_cc<(KT)*64>(loP); } while (0)
#define CONSUME_KT(KT)                                                          \
    do {                                                                        \
        const int wo_##KT = (((KT) * 4 + ks) ^ rswz) << 3;                      \
        s16x8 ah = *(const s16x8*)&whhHi[awB + wo_##KT];                        \
        s16x8 al = *(const s16x8*)&whhLo[awB + wo_##KT];                        \
        gA = MFMA_BF16(ah, bh[KT], gA, 0, 0, 0);                                \
        gB = MFMA_BF16(ah, bl[KT], gB, 0, 0, 0);                                \
        gC = MFMA_BF16(al, bh[KT], gC, 0, 0, 0);                                \
        if (dec) {                                                              \
            s16x8 fh = *(const s16x8*)&wfcHi[awB + wo_##KT];                    \
            s16x8 fl = *(const s16x8*)&wfcLo[awB + wo_##KT];                    \
            pA = MFMA_BF16(fh, bh[KT], pA, 0, 0, 0);                            \
            pB = MFMA_BF16(fh, bl[KT], pB, 0, 0, 0);                            \
            pC = MFMA_BF16(fl, bh[KT], pC, 0, 0, 0);                            \
        }                                                                       \
    } while (0)

    #pragma unroll 1
    for (int tt = 0; tt < TSEQ + FUT; ++tt) {
        const bool dec = (tt >= TSEQ);
        const u16* hiP = (tt & 1) ? hiP1 : hiP0;
        const u16* loP = (tt & 1) ? loP1 : loP0;
        u16* wHi = (tt & 1) ? hHi0 : hHi1;
        u16* wLo = (tt & 1) ? hLo0 : hLo1;

        f32x4 gA = {0,0,0,0}, gB = {0,0,0,0}, gC = {0,0,0,0};
        f32x4 pA = {0,0,0,0}, pB = {0,0,0,0}, pC = {0,0,0,0};
        s16x8 bh[16], bl[16];
        f32x4 xv0 = {0,0,0,0}, xv1 = {0,0,0,0};

        if (!dec) {
            const float* xp = xbase + (size_t)tt * ISZ;
            xv0 = ldx16<0>(xp); xv1 = ldx16<16>(xp);
        }
        ISSUE_KT(0);  ISSUE_KT(1);  ISSUE_KT(2);  ISSUE_KT(3);
        ISSUE_KT(4);  ISSUE_KT(5);  ISSUE_KT(6);  ISSUE_KT(7);
        ISSUE_KT(8);  ISSUE_KT(9);  ISSUE_KT(10); ISSUE_KT(11);
        ISSUE_KT(12); ISSUE_KT(13); ISSUE_KT(14); ISSUE_KT(15);

        if (!dec) {
            WAITV(32);   // x done (32 B-loads still in flight)
            float xv[8];
            *(f32x4*)&xv[0] = xv0; *(f32x4*)&xv[4] = xv1;
            s16x8 xh, xl;
            uint32* ph = (uint32*)&xh; uint32* pl = (uint32*)&xl;
            #pragma unroll
            for (int q = 0; q < 4; ++q) {
                uint32 u0 = __float_as_uint(xv[2*q]),   h0 = u0 & 0xFFFF0000u;
                uint32 u1 = __float_as_uint(xv[2*q+1]), h1 = u1 & 0xFFFF0000u;
                float r0 = xv[2*q]   - __uint_as_float(h0);
                float r1 = xv[2*q+1] - __uint_as_float(h1);
                ph[q] = (h0 >> 16) | h1;
                pl[q] = (__float_as_uint(r0) >> 16) | (__float_as_uint(r1) & 0xFFFF0000u);
            }
            gA = MFMA_BF16(ihH, xh, gA, 0, 0, 0);
            gB = MFMA_BF16(ihH, xl, gB, 0, 0, 0);
            gC = MFMA_BF16(ihL, xh, gC, 0, 0, 0);
        }

        WAITV(24); CONSUME_KT(0);  CONSUME_KT(1);  CONSUME_KT(2);  CONSUME_KT(3);
        WAITV(16); CONSUME_KT(4);  CONSUME_KT(5);  CONSUME_KT(6);  CONSUME_KT(7);
        WAITV(8);  CONSUME_KT(8);  CONSUME_KT(9);  CONSUME_KT(10); CONSUME_KT(11);
        WAITV(0);  CONSUME_KT(12); CONSUME_KT(13); CONSUME_KT(14); CONSUME_KT(15);

        if (dec) {
            // pred epilogue: pred = h@Wfc^T + b_fc  (this WG's 64 batch cols)
            f32x4 pr = pA + pB + pC;
            const int step = tt - TSEQ;
            #pragma unroll
            for (int q = 0; q < 4; ++q) {
                float pv = pr[q] + pb[q];
                int oc = m * 16 + ks * 4 + q;
                uint32 u = __float_as_uint(pv), hu = u & 0xFFFF0000u;
                float rs = pv - __uint_as_float(hu);
                predH[(n << 4) + lcol][oc] = (u16)(u >> 16);
                predL[(n << 4) + lcol][oc] = (u16)(__float_as_uint(rs) >> 16);
                if (ng == 0) outp[(size_t)step * OSZ + oc] = pv;
            }
            __syncthreads();
            s16x8 bhp = *(const s16x8*)&predH[(n << 4) + lcol][ks * 8];
            s16x8 blp = *(const s16x8*)&predL[(n << 4) + lcol][ks * 8];
            gA = MFMA_BF16(ihH, bhp, gA, 0, 0, 0);
            gB = MFMA_BF16(ihH, blp, gB, 0, 0, 0);
            gC = MFMA_BF16(ihL, bhp, gC, 0, 0, 0);
        }

        // ---- gate combine -> LDS bounce -> cell update -> publish h planes ----
        f32x4 gt = gA + gB + gC;
        #pragma unroll
        for (int q = 0; q < 4; ++q)
            gatebuf[m * 16 + ks * 4 + q][(n << 4) + lcol] = gt[q];
        __syncthreads();

        {
            float gi = gatebuf[h8][be] + bi;
            float gf = gatebuf[h8 + 8][be] + bf;
            float gg = gatebuf[h8 + 16][be] + bgg;
            float go = gatebuf[h8 + 24][be] + bo;
            cst = sigm(gf) * cst + sigm(gi) * tanhf(gg);
            float hv = sigm(go) * tanhf(cst);
            uint32 u = __float_as_uint(hv);
            float rs = hv - __uint_as_float(u & 0xFFFF0000u);
            st16_cc(wHi + hoff, u >> 16);
            st16_cc(wLo + hoff, __float_as_uint(rs) >> 16);
        }

        // ---- barrier: drain stores -> post slot -> all-poll 64 slots ----
        asm volatile("s_waitcnt vmcnt(0)" ::: "memory");
        __syncthreads();
        const uint32 token = (uint32)tt + 1u;
        if (tid == 0) st32_cc(myslot, token);
        if (tid < 64) {
            const uint32* sl = pollbase + (tid << 4);
            int guard = 0;
            for (;;) {
                uint32 v = ld32_cc(sl);
                asm volatile("s_waitcnt vmcnt(0)" ::: "memory");
                if (__all(v >= token) || guard > (1 << 20)) break;
                __builtin_amdgcn_s_sleep(2); ++guard;
            }
        }
        __syncthreads();
    }
#undef ISSUE_KT
#undef CONSUME_KT
}

extern "C" void kernel_launch(void* const* d_in, const int* in_sizes, int n_in,
                              void* d_out, int out_size, void* d_ws, size_t ws_size,
                              hipStream_t stream)
{
    (void)in_sizes; (void)n_in; (void)out_size; (void)ws_size;
    const float* x    = (const float*)d_in[0];
    const float* W_ih = (const float*)d_in[1];
    const float* W_hh = (const float*)d_in[2];
    const float* b_ih = (const float*)d_in[3];
    const float* b_hh = (const float*)d_in[4];
    const float* W_fc = (const float*)d_in[5];
    const float* b_fc = (const float*)d_in[6];
    float* out = (float*)d_out;

    char* ws = (char*)d_ws;
    uint32* arrive = (uint32*)(ws);                       // 16 KB padded slots
    u16* hHi0 = (u16*)(ws + (16u   << 10));               // 256 KB
    u16* hLo0 = (u16*)(ws + (272u  << 10));               // 256 KB
    u16* hHi1 = (u16*)(ws + (528u  << 10));               // 256 KB
    u16* hLo1 = (u16*)(ws + (784u  << 10));               // 256 KB
    u16* WhhH = (u16*)(ws + (1040u << 10));               // 2 MB
    u16* WhhL = (u16*)(ws + (3088u << 10));               // 2 MB
    u16* WihH = (u16*)(ws + (5136u << 10));               // 128 KB
    u16* WihL = (u16*)(ws + (5264u << 10));               // 128 KB
    u16* WfcH = (u16*)(ws + (5392u << 10));               // 32 KB
    u16* WfcL = (u16*)(ws + (5424u << 10));               // 32 KB
    float* bsum = (float*)(ws + (5456u << 10));           // 8 KB

    // zero barrier slots + h buffer 0 (hi+lo) = first 528 KB
    hipMemsetAsync(ws, 0, 528u << 10, stream);

    split_weights<<<4424, 256, 0, stream>>>(W_hh, W_ih, W_fc, b_ih, b_hh,
                                            WhhH, WhhL, WihH, WihL, WfcH, WfcL, bsum);

    lstm_mfma<<<256, 512, 0, stream>>>(x, b_fc, out,
                                       WhhH, WhhL, WihH, WihL, WfcH, WfcL, bsum,
                                       hHi0, hLo0, hHi1, hLo1, arrive);
}

// Round 5
// 2739.505 us; speedup vs baseline: 7.4209x; 1.3851x over previous
//
#include <hip/hip_runtime.h>
#include <cmath>

#define TSEQ  256
#define ISZ   32
#define HSZ   512
#define OSZ   32
#define FUT   128

typedef float  f32x4 __attribute__((ext_vector_type(4)));
typedef short  s16x8 __attribute__((ext_vector_type(8)));
typedef unsigned int   uint32;
typedef unsigned int   u32x4 __attribute__((ext_vector_type(4)));
typedef unsigned short u16;

#define MFMA_BF16 __builtin_amdgcn_mfma_f32_16x16x32_bf16

__device__ __forceinline__ float sigm(float v) { return 1.0f / (1.0f + __expf(-v)); }

// MALL-coherent (cross-XCD) access: sc0 sc1 bypass L1+L2.
template<int OFF>
__device__ __forceinline__ u32x4 ldH_cc(const uint32* p) {
    u32x4 d;
    asm volatile("global_load_dwordx4 %0, %1, off offset:%2 sc0 sc1"
                 : "=v"(d) : "v"(p), "n"(OFF) : "memory");
    return d;
}
template<int OFF>
__device__ __forceinline__ f32x4 ldX(const float* p) {   // normal cached
    f32x4 d;
    asm volatile("global_load_dwordx4 %0, %1, off offset:%2"
                 : "=v"(d) : "v"(p), "n"(OFF) : "memory");
    return d;
}
__device__ __forceinline__ void st32_cc(uint32* p, uint32 v) {
    asm volatile("global_store_dword %0, %1, off sc0 sc1" :: "v"(p), "v"(v) : "memory");
}
__device__ __forceinline__ uint32 ld32_cc(const uint32* p) {
    uint32 d;
    asm volatile("global_load_dword %0, %1, off sc0 sc1" : "=v"(d) : "v"(p) : "memory");
    return d;
}
#define WAITV(N) do { asm volatile("s_waitcnt vmcnt(" #N ")" ::: "memory"); \
                      __builtin_amdgcn_sched_barrier(0); } while (0)

// ---------------- weight pre-split: fp32 -> (bf16 hi, bf16 lo) planes ----------------
__global__ __launch_bounds__(256) void split_weights(
    const float* __restrict__ Whh, const float* __restrict__ Wih,
    const float* __restrict__ Wfc, const float* __restrict__ bih,
    const float* __restrict__ bhh,
    u16* WhhH, u16* WhhL, u16* WihH, u16* WihL, u16* WfcH, u16* WfcL,
    float* bsum)
{
    const int i = blockIdx.x * 256 + (int)threadIdx.x;
    if (i < 1048576) {
        float v = Whh[i];
        uint32 u = __float_as_uint(v), hu = u & 0xFFFF0000u;
        float rs = v - __uint_as_float(hu);
        WhhH[i] = (u16)(u >> 16); WhhL[i] = (u16)(__float_as_uint(rs) >> 16);
    } else if (i < 1114112) {
        int j = i - 1048576;
        float v = Wih[j];
        uint32 u = __float_as_uint(v), hu = u & 0xFFFF0000u;
        float rs = v - __uint_as_float(hu);
        WihH[j] = (u16)(u >> 16); WihL[j] = (u16)(__float_as_uint(rs) >> 16);
    } else if (i < 1130496) {
        int j = i - 1114112;
        float v = Wfc[j];
        uint32 u = __float_as_uint(v), hu = u & 0xFFFF0000u;
        float rs = v - __uint_as_float(hu);
        WfcH[j] = (u16)(u >> 16); WfcL[j] = (u16)(__float_as_uint(rs) >> 16);
    } else if (i < 1132544) {
        int j = i - 1130496;
        bsum[j] = bih[j] + bhh[j];
    }
}

// ---------------- persistent MFMA LSTM, R=32 x C=8 ----------------
// grid 256 = cg(8 col groups x 32 batch) x rg(32 unit groups x 16 hidden units)
// block 512 = 8 waves: wave w -> (mr = w>>1 = gate, nc = w&1 = col half).
// Whh fragments live in VGPRs (128 regs). h exchanged as fused u32 (hi16|lo16)
// [col][k] via sc0/sc1; staged once per WG into LDS bf16 planes (swizzled).
// Barrier: per-cg monotonic atomic counter in MALL.
__global__ __launch_bounds__(512, 1) void lstm_mfma2(
    const float* __restrict__ x, const float* __restrict__ b_fc,
    float* __restrict__ out,
    const u16* __restrict__ WhhHg, const u16* __restrict__ WhhLg,
    const u16* __restrict__ WihHg, const u16* __restrict__ WihLg,
    const u16* __restrict__ WfcHg, const u16* __restrict__ WfcLg,
    const float* __restrict__ bsum,
    uint32* hG0, uint32* hG1, uint32* ctr)
{
    __shared__ __align__(16) u16 bHi[2][32][256];   // [half][col][k-swz]
    __shared__ __align__(16) u16 bLo[2][32][256];
    __shared__ float gatebuf[64][33];
    __shared__ __align__(16) u16 predH[32][40];
    __shared__ __align__(16) u16 predL[32][40];

    const int tid  = (int)threadIdx.x;
    const int cg   = (int)blockIdx.x & 7;
    const int rg   = (int)blockIdx.x >> 3;
    const int w    = tid >> 6, lane = tid & 63;
    const int mr   = w >> 1, nc = w & 1;            // mr = gate index 0..3
    const int ks   = lane >> 4, lcol = lane & 15;
    const int ncol = nc * 16 + lcol;                // local batch col 0..31
    const bool predw = (w < 4);                     // waves computing pred (pm=mr)
    const int prow = mr * 16 + lcol;                // pred output row (w<4)

    // A rows: gate mr, unit rg*16 + lcol
    const int grow = mr * HSZ + rg * 16 + lcol;

    // ---- Whh / Wih fragments -> registers (fixed for all 384 steps) ----
    s16x8 wH[16], wL[16];
    #pragma unroll
    for (int kt = 0; kt < 16; ++kt) {
        wH[kt] = *(const s16x8*)(WhhHg + (size_t)grow * HSZ + kt * 32 + ks * 8);
        wL[kt] = *(const s16x8*)(WhhLg + (size_t)grow * HSZ + kt * 32 + ks * 8);
    }
    const s16x8 ihH = *(const s16x8*)(WihHg + (size_t)grow * ISZ + ks * 8);
    const s16x8 ihL = *(const s16x8*)(WihLg + (size_t)grow * ISZ + ks * 8);

    // ---- staging / epilogue thread mapping: col = tid>>4, sub = tid&15 ----
    const int scol = tid >> 4, sli = tid & 15;
    const uint32* sb0 = hG0 + (size_t)(cg * 32 + scol) * HSZ + sli * 16;
    const uint32* sb1 = hG1 + (size_t)(cg * 32 + scol) * HSZ + sli * 16;
    const size_t hidx = (size_t)(cg * 32 + scol) * HSZ + rg * 16 + sli;
    uint32* hwA = hG1 + hidx;   // write target when tt even
    uint32* hwB = hG0 + hidx;   // write target when tt odd

    const float biv = bsum[           rg * 16 + sli];
    const float bfv = bsum[    HSZ  + rg * 16 + sli];
    const float bgv = bsum[2 * HSZ  + rg * 16 + sli];
    const float bov = bsum[3 * HSZ  + rg * 16 + sli];
    float pbq[4] = {0.f, 0.f, 0.f, 0.f};
    if (predw) {
        #pragma unroll
        for (int q = 0; q < 4; ++q) pbq[q] = b_fc[mr * 16 + ks * 4 + q];
    }

    const float* xbase = x + (size_t)(cg * 32 + ncol) * (TSEQ * ISZ) + ks * 8;
    float* outp = out + (size_t)(cg * 32 + ncol) * (FUT * OSZ);
    uint32* ctrp = ctr + cg * 16;   // 64B-spaced per-cg counters

    float cst = 0.f;
    __syncthreads();

#define STAGE_WR(H)                                                            \
    { _Pragma("unroll")                                                        \
      for (int j = 0; j < 4; ++j) {                                            \
          u32x4 v = sreg[(H) * 4 + j];                                         \
          uint32 h0 = (v[0] >> 16) | (v[1] & 0xFFFF0000u);                     \
          uint32 h1 = (v[2] >> 16) | (v[3] & 0xFFFF0000u);                     \
          uint32 l0 = (v[0] & 0xFFFFu) | (v[1] << 16);                         \
          uint32 l1 = (v[2] & 0xFFFFu) | (v[3] << 16);                         \
          int go = (((sli * 2 + (j >> 1)) ^ (scol & 15)) << 3) + ((j & 1) * 4);\
          *(uint2*)&bHi[H][scol][go] = make_uint2(h0, h1);                     \
          *(uint2*)&bLo[H][scol][go] = make_uint2(l0, l1);                     \
      } }

#define CONS_KT(H, KTL)                                                        \
    { const int g = ((((KTL) * 4) + ks) ^ lcol) << 3;                          \
      s16x8 bh = *(const s16x8*)&bHi[H][ncol][g];                              \
      s16x8 bl = *(const s16x8*)&bLo[H][ncol][g];                              \
      gA = MFMA_BF16(wH[(H) * 8 + (KTL)], bh, gA, 0, 0, 0);                    \
      gB = MFMA_BF16(wH[(H) * 8 + (KTL)], bl, gB, 0, 0, 0);                    \
      gC = MFMA_BF16(wL[(H) * 8 + (KTL)], bh, gC, 0, 0, 0);                    \
      if (dec && predw) {                                                      \
          s16x8 fh = *(const s16x8*)(WfcHg + (size_t)prow * HSZ                \
                                     + ((H) * 8 + (KTL)) * 32 + ks * 8);       \
          s16x8 fl = *(const s16x8*)(WfcLg + (size_t)prow * HSZ                \
                                     + ((H) * 8 + (KTL)) * 32 + ks * 8);       \
          pA = MFMA_BF16(fh, bh, pA, 0, 0, 0);                                 \
          pB = MFMA_BF16(fh, bl, pB, 0, 0, 0);                                 \
          pC = MFMA_BF16(fl, bh, pC, 0, 0, 0);                                 \
      } }
#define CONS_HALF(H) \
    CONS_KT(H,0) CONS_KT(H,1) CONS_KT(H,2) CONS_KT(H,3) \
    CONS_KT(H,4) CONS_KT(H,5) CONS_KT(H,6) CONS_KT(H,7)

    #pragma unroll 1
    for (int tt = 0; tt < TSEQ + FUT; ++tt) {
        const bool dec = (tt >= TSEQ);
        const uint32* sb = (tt & 1) ? sb1 : sb0;
        uint32* hwp = (tt & 1) ? hwB : hwA;

        f32x4 gA = {0,0,0,0}, gB = {0,0,0,0}, gC = {0,0,0,0};
        f32x4 pA = {0,0,0,0}, pB = {0,0,0,0}, pC = {0,0,0,0};
        f32x4 xv0 = {0,0,0,0}, xv1 = {0,0,0,0};

        if (!dec) {   // issue x first (oldest), then stage
            const float* xp = xbase + (size_t)tt * ISZ;
            xv0 = ldX<0>(xp); xv1 = ldX<16>(xp);
        }
        u32x4 sreg[8];
        sreg[0] = ldH_cc<0>(sb);    sreg[1] = ldH_cc<16>(sb);
        sreg[2] = ldH_cc<32>(sb);   sreg[3] = ldH_cc<48>(sb);
        sreg[4] = ldH_cc<1024>(sb); sreg[5] = ldH_cc<1040>(sb);
        sreg[6] = ldH_cc<1056>(sb); sreg[7] = ldH_cc<1072>(sb);

        if (!dec) {
            WAITV(8);   // x done; stage still in flight
            float xv[8];
            *(f32x4*)&xv[0] = xv0; *(f32x4*)&xv[4] = xv1;
            s16x8 xh, xl;
            uint32* ph = (uint32*)&xh; uint32* pl = (uint32*)&xl;
            #pragma unroll
            for (int q = 0; q < 4; ++q) {
                uint32 u0 = __float_as_uint(xv[2*q]),   h0 = u0 & 0xFFFF0000u;
                uint32 u1 = __float_as_uint(xv[2*q+1]), h1 = u1 & 0xFFFF0000u;
                float r0 = xv[2*q]   - __uint_as_float(h0);
                float r1 = xv[2*q+1] - __uint_as_float(h1);
                ph[q] = (h0 >> 16) | h1;
                pl[q] = (__float_as_uint(r0) >> 16) | (__float_as_uint(r1) & 0xFFFF0000u);
            }
            gA = MFMA_BF16(ihH, xh, gA, 0, 0, 0);
            gB = MFMA_BF16(ihH, xl, gB, 0, 0, 0);
            gC = MFMA_BF16(ihL, xh, gC, 0, 0, 0);
        }

        WAITV(4);          // half0 arrived
        STAGE_WR(0);
        __syncthreads();
        CONS_HALF(0);      // half1 still in flight under these MFMAs
        WAITV(0);
        STAGE_WR(1);
        __syncthreads();
        CONS_HALF(1);

        if (dec) {
            // pred = h @ Wfc^T + b_fc (redundant per WG -> no exchange needed)
            f32x4 pr = pA + pB + pC;
            const int step = tt - TSEQ;
            if (predw) {
                #pragma unroll
                for (int q = 0; q < 4; ++q) {
                    float pv = pr[q] + pbq[q];
                    int oc = mr * 16 + ks * 4 + q;
                    uint32 u = __float_as_uint(pv), hu = u & 0xFFFF0000u;
                    float rs = pv - __uint_as_float(hu);
                    predH[ncol][oc] = (u16)(u >> 16);
                    predL[ncol][oc] = (u16)(__float_as_uint(rs) >> 16);
                    if (rg == 0) outp[(size_t)step * OSZ + oc] = pv;
                }
            }
            __syncthreads();
            s16x8 bhp = *(const s16x8*)&predH[ncol][ks * 8];
            s16x8 blp = *(const s16x8*)&predL[ncol][ks * 8];
            gA = MFMA_BF16(ihH, bhp, gA, 0, 0, 0);
            gB = MFMA_BF16(ihH, blp, gB, 0, 0, 0);
            gC = MFMA_BF16(ihL, bhp, gC, 0, 0, 0);
        }

        // ---- gates -> LDS bounce ----
        f32x4 gt = gA + gB + gC;
        #pragma unroll
        for (int q = 0; q < 4; ++q)
            gatebuf[mr * 16 + ks * 4 + q][ncol] = gt[q];
        __syncthreads();

        // ---- cell update (thread = unit sli, col scol) + publish fused h ----
        {
            float gi = gatebuf[     sli][scol] + biv;
            float gf = gatebuf[16 + sli][scol] + bfv;
            float gg = gatebuf[32 + sli][scol] + bgv;
            float go = gatebuf[48 + sli][scol] + bov;
            cst = sigm(gf) * cst + sigm(gi) * tanhf(gg);
            float hv = sigm(go) * tanhf(cst);
            uint32 u = __float_as_uint(hv), hu = u & 0xFFFF0000u;
            float rs = hv - __uint_as_float(hu);
            st32_cc(hwp, hu | (__float_as_uint(rs) >> 16));
        }

        // ---- barrier: drain -> atomic count -> poll one MALL line ----
        WAITV(0);
        __syncthreads();
        if (tid == 0) {
            __hip_atomic_fetch_add(ctrp, 1u, __ATOMIC_RELAXED, __HIP_MEMORY_SCOPE_AGENT);
            const uint32 tgt = 32u * (uint32)(tt + 1);
            int guard = 0;
            for (;;) {
                uint32 v = ld32_cc(ctrp);
                WAITV(0);
                if (v >= tgt || guard > (1 << 20)) break;
                __builtin_amdgcn_s_sleep(1); ++guard;
            }
        }
        __syncthreads();
    }
#undef STAGE_WR
#undef CONS_KT
#undef CONS_HALF
}

extern "C" void kernel_launch(void* const* d_in, const int* in_sizes, int n_in,
                              void* d_out, int out_size, void* d_ws, size_t ws_size,
                              hipStream_t stream)
{
    (void)in_sizes; (void)n_in; (void)out_size; (void)ws_size;
    const float* x    = (const float*)d_in[0];
    const float* W_ih = (const float*)d_in[1];
    const float* W_hh = (const float*)d_in[2];
    const float* b_ih = (const float*)d_in[3];
    const float* b_hh = (const float*)d_in[4];
    const float* W_fc = (const float*)d_in[5];
    const float* b_fc = (const float*)d_in[6];
    float* out = (float*)d_out;

    char* ws = (char*)d_ws;
    uint32* ctr  = (uint32*)(ws);                  // 8 counters, 64B apart
    uint32* hG0  = (uint32*)(ws + 1024);           // 512 KB fused h, buffer 0
    uint32* hG1  = (uint32*)(ws + 1024 + 524288);  // 512 KB fused h, buffer 1
    u16* WhhH = (u16*)(ws + 1049600);              // 2 MB
    u16* WhhL = (u16*)(ws + 3146752);              // 2 MB
    u16* WihH = (u16*)(ws + 5243904);              // 128 KB
    u16* WihL = (u16*)(ws + 5374976);              // 128 KB
    u16* WfcH = (u16*)(ws + 5506048);              // 32 KB
    u16* WfcL = (u16*)(ws + 5538816);              // 32 KB
    float* bsum = (float*)(ws + 5571584);          // 8 KB

    // zero counters + hG0 (initial hidden state)
    hipMemsetAsync(ws, 0, 1024 + 524288, stream);

    split_weights<<<4424, 256, 0, stream>>>(W_hh, W_ih, W_fc, b_ih, b_hh,
                                            WhhH, WhhL, WihH, WihL, WfcH, WfcL, bsum);

    lstm_mfma2<<<256, 512, 0, stream>>>(x, b_fc, out,
                                        WhhH, WhhL, WihH, WihL, WfcH, WfcL, bsum,
                                        hG0, hG1, ctr);
}